// Round 1
// baseline (1183.186 us; speedup 1.0000x reference)
//
#include <hip/hip_runtime.h>

// Differentiable EXP-HYDRO: B=128, T=4096, F=20; MLP(15->256->64->6) + sequential scan.
// K1 mlp_kernel : params for every (b,t) + all step-invariant precomputation -> par AoS[12]
// K2 scan_kernel: 128 independent (s0,s1) chains, one lane each; writes s1 trace
// K3 qout_kernel: q = qsub+qsurf at (s1[t], params[t]); LDS transpose to (B,T) layout

#define BB   128
#define TT   4096
#define NPOS (BB * TT)
#define PSTR 12                       // floats per position in param AoS (48 B)

#define L2E   1.4426950408889634f     // log2(e)
#define L10F  14.426950408889634f     // 10*log2(e)
#define FL2C  0.14426950408889634f    // (1/10)*log2(e)
#define CLIPF 100000.0f

__device__ __forceinline__ float fexp2(float x) { return __builtin_amdgcn_exp2f(x); }
__device__ __forceinline__ float frcp(float x)  { return __builtin_amdgcn_rcpf(x); }
// heaviside(x) = (tanh(5x)+1)/2 = sigmoid(10x)
__device__ __forceinline__ float sig10(float x) { return frcp(1.0f + fexp2(-L10F * x)); }
__device__ __forceinline__ float sigm(float x)  { return frcp(1.0f + fexp2(-L2E * x)); }
__device__ __forceinline__ float tanh_fast(float x) {
    // tanh(x) = 1 - 2/(exp2(2*log2e*x)+1); saturates correctly via inf/0
    float e = fexp2(2.0f * L2E * x);
    return 1.0f - 2.0f * frcp(e + 1.0f);
}

// ---------------------------------------------------------------- K1: MLP ----
__global__ __launch_bounds__(512) void mlp_kernel(
    const float* __restrict__ inp, const float* __restrict__ w1,
    const float* __restrict__ b1,  const float* __restrict__ w2,
    const float* __restrict__ b2,  const float* __restrict__ w3,
    const float* __restrict__ b3,  float* __restrict__ par)
{
    __shared__ float lw1[15 * 256];
    __shared__ float lw2[256 * 64];
    __shared__ float lw3[64 * 6];
    __shared__ float lb1[256];
    __shared__ float lb2[64];
    __shared__ float lb3[8];

    const int tid = threadIdx.x;
    for (int i = tid; i < 15 * 256 / 4; i += 512)
        ((float4*)lw1)[i] = ((const float4*)w1)[i];
    for (int i = tid; i < 256 * 64 / 4; i += 512)
        ((float4*)lw2)[i] = ((const float4*)w2)[i];
    if (tid < 64 * 6) lw3[tid] = w3[tid];
    if (tid < 256)    lb1[tid] = b1[tid];
    if (tid < 64)     lb2[tid] = b2[tid];
    if (tid < 8)      lb3[tid] = (tid < 6) ? b3[tid] : 0.0f;
    __syncthreads();

    const int pos = blockIdx.x * 512 + tid;   // pos = t*128 + b  (b fastest)
    const int b   = pos & 127;
    const int t   = pos >> 7;

    const float4* xin = (const float4*)(inp + ((size_t)b * TT + t) * 20);
    float4 i0 = xin[0], i1 = xin[1], i2 = xin[2], i3 = xin[3], i4 = xin[4];
    const float pet = i0.x, tme = i0.y, prcp = i0.z;
    float x[15];
    x[0]=i1.y;  x[1]=i1.z;  x[2]=i1.w;
    x[3]=i2.x;  x[4]=i2.y;  x[5]=i2.z;  x[6]=i2.w;
    x[7]=i3.x;  x[8]=i3.y;  x[9]=i3.z;  x[10]=i3.w;
    x[11]=i4.x; x[12]=i4.y; x[13]=i4.z; x[14]=i4.w;

    float acc2[64];
    #pragma unroll
    for (int j = 0; j < 64; ++j) acc2[j] = lb2[j];

    #pragma unroll 1
    for (int c = 0; c < 8; ++c) {             // 8 chunks of 32 hidden units
        float h[32];
        #pragma unroll
        for (int j = 0; j < 32; ++j) {
            const int col = c * 32 + j;
            float pre = lb1[col];
            #pragma unroll
            for (int k = 0; k < 15; ++k) pre = fmaf(x[k], lw1[k * 256 + col], pre);
            h[j] = tanh_fast(pre);
        }
        #pragma unroll
        for (int k2 = 0; k2 < 32; ++k2) {
            const float* wr = &lw2[(c * 32 + k2) * 64];
            const float hv = h[k2];
            #pragma unroll
            for (int j4 = 0; j4 < 16; ++j4) {
                float4 wv = *(const float4*)(wr + j4 * 4);
                acc2[j4*4+0] = fmaf(hv, wv.x, acc2[j4*4+0]);
                acc2[j4*4+1] = fmaf(hv, wv.y, acc2[j4*4+1]);
                acc2[j4*4+2] = fmaf(hv, wv.z, acc2[j4*4+2]);
                acc2[j4*4+3] = fmaf(hv, wv.w, acc2[j4*4+3]);
            }
        }
    }

    float p[6];
    #pragma unroll
    for (int o = 0; o < 6; ++o) p[o] = lb3[o];
    #pragma unroll
    for (int j = 0; j < 64; ++j) {
        const float h2 = tanh_fast(acc2[j]);
        #pragma unroll
        for (int o = 0; o < 6; ++o) p[o] = fmaf(h2, lw3[j * 6 + o], p[o]);
    }
    const float tmin_p = sigm(p[0]), tmax_p = sigm(p[1]), ddf_p = sigm(p[2]);
    const float f_p    = sigm(p[3]), smax_p = sigm(p[4]), qmax_p = sigm(p[5]);

    // step-invariant precomputation
    const float tmn   = -3.0f * tmin_p;
    const float g     = sig10(tmn - tme);
    const float psnow = g * prcp;
    const float prain = prcp - psnow;
    const float tmx3  = 3.0f * tmax_p;
    const float hm    = sig10(tme - tmx3);
    const float dd    = 5.0f * ddf_p * (tme - tmx3);
    const float smax  = fmaf(1400.0f, smax_p, 100.0f);
    const float pr    = pet * frcp(smax);          // pet/smax
    const float qmax  = fmaf(40.0f, qmax_p, 10.0f);
    const float fl2   = FL2C * f_p;                // (f/10)*log2e
    const float l10smax = L10F * smax;
    const float flsmax  = fl2 * smax;

    float* o = par + (size_t)pos * PSTR;
    *(float4*)(o + 0) = make_float4(psnow, prain, hm, dd);
    *(float4*)(o + 4) = make_float4(pet, pr, qmax, fl2);
    *(float4*)(o + 8) = make_float4(smax, l10smax, flsmax, 0.0f);
}

// --------------------------------------------------------------- K2: scan ----
#define SC     4        // timesteps per chunk
#define NCHUNK (TT / SC)

#define LOADC(c, N) { _Pragma("unroll")                                          \
    for (int s_ = 0; s_ < SC; ++s_) {                                            \
        const float4* q_ = (const float4*)(par +                                 \
            (size_t)(((c) * SC + s_) * 128 + b) * PSTR);                         \
        N##0[s_] = q_[0]; N##1[s_] = q_[1]; N##2[s_] = q_[2];                    \
    } }

#define COMPC(c, N) { _Pragma("unroll")                                          \
    for (int s_ = 0; s_ < SC; ++s_) {                                            \
        const float psnow = N##0[s_].x, prain = N##0[s_].y;                      \
        const float hm = N##0[s_].z, dd = N##0[s_].w;                            \
        const float pet = N##1[s_].x, pr = N##1[s_].y;                           \
        const float qmaxv = N##1[s_].z, fl2 = N##1[s_].w;                        \
        const float smaxv = N##2[s_].x, l10smax = N##2[s_].y;                    \
        const float flsmax = N##2[s_].z;                                         \
        /* snow bucket (independent of s1) */                                    \
        const float h0   = frcp(1.0f + fexp2(-L10F * s0));                       \
        const float melt = hm * h0 * fminf(s0, dd);                              \
        const float ds0  = psnow - melt;                                         \
        s0 = s0 + fminf(fmaxf(ds0, -CLIPF), CLIPF);                              \
        /* soil bucket: et+qsub+qsurf = h1*(ha*G + H) */                         \
        const float a  = s1 - smaxv;                                             \
        const float u  = s1 * pr;                                                \
        const float h1 = frcp(1.0f + fexp2(-L10F * s1));                         \
        const float ha = frcp(1.0f + fexp2(fmaf(-L10F, s1, l10smax)));           \
        const float ez = fexp2(fmaf(fl2, s1, -flsmax));                          \
        const float w  = qmaxv * ez;                                             \
        const float G  = (pet - u) + (qmaxv - w) + a;                            \
        const float H  = u + w;                                                  \
        const float ds1 = (prain + melt) - h1 * fmaf(ha, G, H);                  \
        s1 = s1 + fminf(fmaxf(ds1, -CLIPF), CLIPF);                              \
        s1buf[(size_t)(((c) * SC + s_) * 128 + b)] = s1;                         \
    } }

__global__ __launch_bounds__(128) void scan_kernel(
    const float* __restrict__ par, float* __restrict__ s1buf)
{
    const int b = threadIdx.x;      // one chain per lane
    float s0 = 0.0f, s1 = 0.0f;

    float4 A0[SC], A1[SC], A2[SC];
    float4 B0[SC], B1[SC], B2[SC];
    float4 C0[SC], C1[SC], C2[SC];

    LOADC(0, A);
    LOADC(1, B);
    int c = 0;
    for (int it = 0; it < 341; ++it) {      // 341*3 = 1023 chunks in rotation
        LOADC(c + 2, C);
        COMPC(c, A);
        LOADC(c + 3, A);                    // c+3 <= 1023 always: valid
        COMPC(c + 1, B);
        if (it < 340) { LOADC(c + 4, B); }  // c+4 == 1024 on last iter: skip
        COMPC(c + 2, C);
        c += 3;
    }
    COMPC(1023, A);                          // final chunk (in A)
}

// --------------------------------------------------------------- K3: qout ----
__global__ __launch_bounds__(1024) void qout_kernel(
    const float* __restrict__ par, const float* __restrict__ s1buf,
    float* __restrict__ out)
{
    __shared__ float tile[32][33];           // +1 pad: conflict-free transpose
    const int tid = threadIdx.x;
    const int b0  = (blockIdx.x & 3) * 32;
    const int t0  = (blockIdx.x >> 2) * 32;

    // load phase: lanes sweep b (coalesced in the [t][b] layout)
    const int bl = tid & 31, tl = tid >> 5;
    const int pos = (t0 + tl) * 128 + (b0 + bl);
    const float s1 = s1buf[pos];
    const float* pp = par + (size_t)pos * PSTR;
    float4 v1 = *(const float4*)(pp + 4);    // pet, pr, qmax, fl2
    float4 v2 = *(const float4*)(pp + 8);    // smax, l10smax, flsmax, pad
    const float qmax = v1.z, fl2 = v1.w;
    const float smax = v2.x, l10smax = v2.y, flsmax = v2.z;

    const float a  = s1 - smax;
    const float h1 = frcp(1.0f + fexp2(-L10F * s1));
    const float ha = frcp(1.0f + fexp2(fmaf(-L10F, s1, l10smax)));
    const float ez = fexp2(fmaf(fl2, s1, -flsmax));
    const float w  = qmax * ez;
    const float q  = h1 * (fmaf(ha, (qmax - w) + a, w));   // qsub + qsurf

    tile[tl][bl] = q;
    __syncthreads();

    // store phase: lanes sweep t (coalesced in the output [b][t] layout)
    const int tl2 = tid & 31, bl2 = tid >> 5;
    out[(size_t)(b0 + bl2) * TT + (t0 + tl2)] = tile[tl2][bl2];
}

// ------------------------------------------------------------------ launch ---
extern "C" void kernel_launch(void* const* d_in, const int* in_sizes, int n_in,
                              void* d_out, int out_size, void* d_ws, size_t ws_size,
                              hipStream_t stream)
{
    (void)in_sizes; (void)n_in; (void)out_size; (void)ws_size;
    const float* inp = (const float*)d_in[0];
    const float* w1  = (const float*)d_in[1];
    const float* b1  = (const float*)d_in[2];
    const float* w2  = (const float*)d_in[3];
    const float* b2  = (const float*)d_in[4];
    const float* w3  = (const float*)d_in[5];
    const float* b3  = (const float*)d_in[6];
    float* out   = (float*)d_out;
    float* par   = (float*)d_ws;                       // NPOS*12 floats = 25.2 MB
    float* s1buf = (float*)d_ws + (size_t)NPOS * PSTR; // NPOS floats   =  2.0 MB

    hipLaunchKernelGGL(mlp_kernel, dim3(NPOS / 512), dim3(512), 0, stream,
                       inp, w1, b1, w2, b2, w3, b3, par);
    hipLaunchKernelGGL(scan_kernel, dim3(1), dim3(128), 0, stream, par, s1buf);
    hipLaunchKernelGGL(qout_kernel, dim3((BB / 32) * (TT / 32)), dim3(1024), 0, stream,
                       par, s1buf, out);
}

// Round 3
// 773.704 us; speedup vs baseline: 1.5292x; 1.5292x over previous
//
#include <hip/hip_runtime.h>

// Differentiable EXP-HYDRO: B=128, T=4096, F=20; MLP(15->256->64->6) + sequential scan.
// K1 mlp_kernel : params for every (b,t) + step-invariant precompute -> par AoS[12]
//                 (weights read via wave-uniform global loads -> SMEM s_load path)
// K2 scan_kernel: 128 chains split over 2 blocks x 64 lanes; writes s1 trace
// K3 qout_kernel: q = qsub+qsurf at (s1[t], params[t]); LDS transpose to (B,T)

#define BB   128
#define TT   4096
#define NPOS (BB * TT)
#define PSTR 12                       // floats per position in param AoS (48 B)

#define L2E   1.4426950408889634f     // log2(e)
#define L10F  14.426950408889634f     // 10*log2(e)
#define FL2C  0.14426950408889634f    // (1/10)*log2(e)
#define CLIPF 100000.0f

__device__ __forceinline__ float fexp2(float x) { return __builtin_amdgcn_exp2f(x); }
__device__ __forceinline__ float frcp(float x)  { return __builtin_amdgcn_rcpf(x); }
// heaviside(x) = (tanh(5x)+1)/2 = sigmoid(10x)
__device__ __forceinline__ float sig10(float x) { return frcp(1.0f + fexp2(-L10F * x)); }
__device__ __forceinline__ float sigm(float x)  { return frcp(1.0f + fexp2(-L2E * x)); }
__device__ __forceinline__ float tanh_fast(float x) {
    float e = fexp2(2.0f * L2E * x);
    return 1.0f - 2.0f * frcp(e + 1.0f);
}

// ---------------------------------------------------------------- K1: MLP ----
// No LDS: weight accesses use compile-time-uniform indices on const __restrict__
// pointers -> compiler emits scalar (SMEM) loads; VALU pipe stays free for FMAs.
__global__ __launch_bounds__(256) void mlp_kernel(
    const float* __restrict__ inp, const float* __restrict__ w1,
    const float* __restrict__ b1,  const float* __restrict__ w2,
    const float* __restrict__ b2,  const float* __restrict__ w3,
    const float* __restrict__ b3,  float* __restrict__ par)
{
    const int pos = blockIdx.x * 256 + threadIdx.x;   // pos = t*128 + b (b fastest)
    const int b   = pos & 127;
    const int t   = pos >> 7;

    const float4* xin = (const float4*)(inp + ((size_t)b * TT + t) * 20);
    float4 i0 = xin[0], i1 = xin[1], i2 = xin[2], i3 = xin[3], i4 = xin[4];
    const float pet = i0.x, tme = i0.y, prcp = i0.z;
    float x[15];
    x[0]=i1.y;  x[1]=i1.z;  x[2]=i1.w;
    x[3]=i2.x;  x[4]=i2.y;  x[5]=i2.z;  x[6]=i2.w;
    x[7]=i3.x;  x[8]=i3.y;  x[9]=i3.z;  x[10]=i3.w;
    x[11]=i4.x; x[12]=i4.y; x[13]=i4.z; x[14]=i4.w;

    float acc2[64];
    #pragma unroll
    for (int j = 0; j < 64; ++j) acc2[j] = b2[j];

    #pragma unroll 1
    for (int c = 0; c < 8; ++c) {             // 8 chunks of 32 hidden units
        float h[32];
        #pragma unroll
        for (int j = 0; j < 32; ++j) {
            const int col = c * 32 + j;
            float pre = b1[col];
            #pragma unroll
            for (int k = 0; k < 15; ++k) pre = fmaf(x[k], w1[k * 256 + col], pre);
            h[j] = tanh_fast(pre);
        }
        #pragma unroll
        for (int k2 = 0; k2 < 32; ++k2) {
            const float hv = h[k2];
            const int row = (c * 32 + k2) * 64;
            #pragma unroll
            for (int j = 0; j < 64; ++j)
                acc2[j] = fmaf(hv, w2[row + j], acc2[j]);
        }
    }

    float p[6];
    #pragma unroll
    for (int o = 0; o < 6; ++o) p[o] = b3[o];
    #pragma unroll
    for (int j = 0; j < 64; ++j) {
        const float h2 = tanh_fast(acc2[j]);
        #pragma unroll
        for (int o = 0; o < 6; ++o) p[o] = fmaf(h2, w3[j * 6 + o], p[o]);
    }
    const float tmin_p = sigm(p[0]), tmax_p = sigm(p[1]), ddf_p = sigm(p[2]);
    const float f_p    = sigm(p[3]), smax_p = sigm(p[4]), qmax_p = sigm(p[5]);

    // step-invariant precompute
    const float tmn   = -3.0f * tmin_p;
    const float g     = sig10(tmn - tme);
    const float psnow = g * prcp;
    const float prain = prcp - psnow;
    const float tmx3  = 3.0f * tmax_p;
    const float hm    = sig10(tme - tmx3);
    const float dd    = 5.0f * ddf_p * (tme - tmx3);
    const float smax  = fmaf(1400.0f, smax_p, 100.0f);
    const float qmax  = fmaf(40.0f, qmax_p, 10.0f);
    const float pr    = pet * frcp(smax);          // pet/smax
    const float pr2   = 1.0f - pr;
    const float C1    = pet + qmax - smax;
    const float fl2   = FL2C * f_p;                // (f/10)*log2e
    const float flsmax  = fl2 * smax;
    const float l10smax = L10F * smax;

    float* o = par + (size_t)pos * PSTR;
    *(float4*)(o + 0) = make_float4(psnow, prain, hm, dd);
    *(float4*)(o + 4) = make_float4(C1, pr, pr2, qmax);
    *(float4*)(o + 8) = make_float4(fl2, flsmax, l10smax, smax);
}

// --------------------------------------------------------------- K2: scan ----
#define SC     4        // timesteps per chunk
#define NCHUNK (TT / SC)

#define LOADC(cc, N) { _Pragma("unroll")                                         \
    for (int s_ = 0; s_ < SC; ++s_) {                                            \
        const float4* q_ = (const float4*)(par +                                 \
            (size_t)(((cc) * SC + s_) * 128 + chain) * PSTR);                    \
        N##0[s_] = q_[0]; N##1[s_] = q_[1]; N##2[s_] = q_[2];                    \
    } }

#define COMPC(cc, N) { _Pragma("unroll")                                         \
    for (int s_ = 0; s_ < SC; ++s_) {                                            \
        const float psnow = N##0[s_].x, prain = N##0[s_].y;                      \
        const float hm = N##0[s_].z, dd = N##0[s_].w;                            \
        const float C1 = N##1[s_].x, pr = N##1[s_].y;                            \
        const float pr2 = N##1[s_].z, qmaxv = N##1[s_].w;                        \
        const float fl2 = N##2[s_].x, flsmax = N##2[s_].y;                       \
        const float l10smax = N##2[s_].z;                                        \
        /* snow bucket */                                                        \
        const float h0   = frcp(1.0f + fexp2(-L10F * s0));                       \
        const float melt = hm * h0 * fminf(s0, dd);                              \
        s0 = s0 + fminf(fmaxf(psnow - melt, -CLIPF), CLIPF);                     \
        /* soil bucket: et+qsub+qsurf = h1*(ha*G + H) */                         \
        const float h1 = frcp(1.0f + fexp2(-L10F * s1));                         \
        const float ha = frcp(1.0f + fexp2(fmaf(-L10F, s1, l10smax)));           \
        const float ez = fexp2(fmaf(fl2, s1, -flsmax));                          \
        const float w  = qmaxv * ez;                                             \
        const float G  = fmaf(s1, pr2, C1) - w;                                  \
        const float H  = fmaf(s1, pr, w);                                        \
        const float ds1 = fmaf(-h1, fmaf(ha, G, H), prain + melt);               \
        s1 = s1 + fminf(fmaxf(ds1, -CLIPF), CLIPF);                              \
        s1buf[(size_t)(((cc) * SC + s_) * 128 + chain)] = s1;                    \
    } }

__global__ __launch_bounds__(64) void scan_kernel(
    const float* __restrict__ par, float* __restrict__ s1buf)
{
    const int chain = blockIdx.x * 64 + threadIdx.x;   // 2 blocks x 64 chains
    float s0 = 0.0f, s1 = 0.0f;

    float4 A0[SC], A1[SC], A2[SC];
    float4 B0[SC], B1[SC], B2[SC];
    float4 C0[SC], C1v[SC], C2[SC];
    // C1v to avoid clash with the C1 field name inside COMPC
#define C1 C1v
    LOADC(0, A);
    LOADC(1, B);
#undef C1

    int c = 0;
    for (int it = 0; it < 341; ++it) {      // 341*3 = 1023 chunks in rotation
#define C1 C1v
        LOADC(c + 2, C);
#undef C1
        COMPC(c, A);
        LOADC(c + 3, A);                    // c+3 <= 1023 always: valid
        COMPC(c + 1, B);
        if (it < 340) { LOADC(c + 4, B); }  // c+4 == 1024 on last iter: skip
        {
            // compute chunk c+2 from C buffers
            #pragma unroll
            for (int s_ = 0; s_ < SC; ++s_) {
                const float psnow = C0[s_].x, prain = C0[s_].y;
                const float hm = C0[s_].z, dd = C0[s_].w;
                const float C1f = C1v[s_].x, pr = C1v[s_].y;
                const float pr2 = C1v[s_].z, qmaxv = C1v[s_].w;
                const float fl2 = C2[s_].x, flsmax = C2[s_].y;
                const float l10smax = C2[s_].z;
                const float h0   = frcp(1.0f + fexp2(-L10F * s0));
                const float melt = hm * h0 * fminf(s0, dd);
                s0 = s0 + fminf(fmaxf(psnow - melt, -CLIPF), CLIPF);
                const float h1 = frcp(1.0f + fexp2(-L10F * s1));
                const float ha = frcp(1.0f + fexp2(fmaf(-L10F, s1, l10smax)));
                const float ez = fexp2(fmaf(fl2, s1, -flsmax));
                const float w  = qmaxv * ez;
                const float G  = fmaf(s1, pr2, C1f) - w;
                const float H  = fmaf(s1, pr, w);
                const float ds1 = fmaf(-h1, fmaf(ha, G, H), prain + melt);
                s1 = s1 + fminf(fmaxf(ds1, -CLIPF), CLIPF);
                s1buf[(size_t)(((c + 2) * SC + s_) * 128 + chain)] = s1;
            }
        }
        c += 3;
    }
    COMPC(1023, A);                          // final chunk (in A)
}

// --------------------------------------------------------------- K3: qout ----
__global__ __launch_bounds__(1024) void qout_kernel(
    const float* __restrict__ par, const float* __restrict__ s1buf,
    float* __restrict__ out)
{
    __shared__ float tile[32][33];           // +1 pad: conflict-free transpose
    const int tid = threadIdx.x;
    const int b0  = (blockIdx.x & 3) * 32;
    const int t0  = (blockIdx.x >> 2) * 32;

    const int bl = tid & 31, tl = tid >> 5;
    const int pos = (t0 + tl) * 128 + (b0 + bl);
    const float s1 = s1buf[pos];
    const float* pp = par + (size_t)pos * PSTR;
    float4 v1 = *(const float4*)(pp + 4);    // C1, pr, pr2, qmax
    float4 v2 = *(const float4*)(pp + 8);    // fl2, flsmax, l10smax, smax
    const float qmax = v1.w;
    const float fl2 = v2.x, flsmax = v2.y, l10smax = v2.z, smax = v2.w;

    const float a  = s1 - smax;
    const float h1 = frcp(1.0f + fexp2(-L10F * s1));
    const float ha = frcp(1.0f + fexp2(fmaf(-L10F, s1, l10smax)));
    const float ez = fexp2(fmaf(fl2, s1, -flsmax));
    const float w  = qmax * ez;
    const float q  = h1 * (fmaf(ha, (qmax - w) + a, w));   // qsub + qsurf

    tile[tl][bl] = q;
    __syncthreads();

    const int tl2 = tid & 31, bl2 = tid >> 5;
    out[(size_t)(b0 + bl2) * TT + (t0 + tl2)] = tile[tl2][bl2];
}

// ------------------------------------------------------------------ launch ---
extern "C" void kernel_launch(void* const* d_in, const int* in_sizes, int n_in,
                              void* d_out, int out_size, void* d_ws, size_t ws_size,
                              hipStream_t stream)
{
    (void)in_sizes; (void)n_in; (void)out_size; (void)ws_size;
    const float* inp = (const float*)d_in[0];
    const float* w1  = (const float*)d_in[1];
    const float* b1  = (const float*)d_in[2];
    const float* w2  = (const float*)d_in[3];
    const float* b2  = (const float*)d_in[4];
    const float* w3  = (const float*)d_in[5];
    const float* b3  = (const float*)d_in[6];
    float* out   = (float*)d_out;
    float* par   = (float*)d_ws;                       // NPOS*12 floats = 25.2 MB
    float* s1buf = (float*)d_ws + (size_t)NPOS * PSTR; // NPOS floats   =  2.0 MB

    hipLaunchKernelGGL(mlp_kernel, dim3(NPOS / 256), dim3(256), 0, stream,
                       inp, w1, b1, w2, b2, w3, b3, par);
    hipLaunchKernelGGL(scan_kernel, dim3(2), dim3(64), 0, stream, par, s1buf);
    hipLaunchKernelGGL(qout_kernel, dim3((BB / 32) * (TT / 32)), dim3(1024), 0, stream,
                       par, s1buf, out);
}